// Round 1
// baseline (245.636 us; speedup 1.0000x reference)
//
#include <hip/hip_runtime.h>
#include <hip/hip_bf16.h>

// RGCN CSR, two layers, on MI355X.
// Reformulation: h[i] = sum_r (sum_{e in row i, rel=r} x[src_e]) @ W1[r]
//  -> gather kernel builds A[N, R*64] (bf16), then one GEMM with K=512.
// Layer 2 identical with W2 (N=40, padded to 48), log_softmax fused.

typedef __attribute__((ext_vector_type(8))) short short8;
typedef __attribute__((ext_vector_type(4))) float floatx4;

#define DK 512          // R * D = 8 * 64, flattened K dimension

static __device__ __forceinline__ unsigned short f2bf(float f) {
    unsigned u = __float_as_uint(f);
    u += 0x7FFFu + ((u >> 16) & 1u);      // RNE
    return (unsigned short)(u >> 16);
}
static __device__ __forceinline__ float bf2f(unsigned short h) {
    return __uint_as_float(((unsigned)h) << 16);
}

// ---- cast x (f32) -> bf16, 4 elems/thread ----
__global__ void k_cast(const float* __restrict__ x, unsigned short* __restrict__ o, int n4) {
    int i = blockIdx.x * blockDim.x + threadIdx.x;
    if (i >= n4) return;
    float4 v = ((const float4*)x)[i];
    ushort4 r;
    r.x = f2bf(v.x); r.y = f2bf(v.y); r.z = f2bf(v.z); r.w = f2bf(v.w);
    ((ushort4*)o)[i] = r;
}

// ---- pack W1[r][d][f] -> BT1[f][r*64+d] (bf16), W2 likewise into BT2[40][512] ----
__global__ void k_packw(const float* __restrict__ W1, const float* __restrict__ W2,
                        unsigned short* __restrict__ BT1, unsigned short* __restrict__ BT2) {
    int i = blockIdx.x * 256 + threadIdx.x;
    if (i < 64 * 512) {
        int f = i >> 9, rd = i & 511;
        int r = rd >> 6, d = rd & 63;
        BT1[i] = f2bf(W1[(r << 12) + (d << 6) + f]);
    } else if (i < 64 * 512 + 40 * 512) {
        int j = i - 64 * 512;
        int f = j >> 9, rd = j & 511;
        int r = rd >> 6, d = rd & 63;
        BT2[j] = f2bf(W2[r * 2560 + d * 40 + f]);
    }
}

// ---- gather: one wave per destination row; per-relation register accumulators.
// rel is wave-uniform per edge -> readfirstlane + scalar switch (no runtime-indexed
// register array, no LDS). CSR rows contiguous -> no atomics.
__global__ __launch_bounds__(256) void k_gather(
    const unsigned short* __restrict__ src,          // [N, 64] bf16 rows
    const int* __restrict__ ptr, const int* __restrict__ idx,
    const int* __restrict__ rel,
    unsigned short* __restrict__ A, int nrows) {     // [Mp, 512] bf16
    int row = blockIdx.x * 4 + (threadIdx.x >> 6);
    int lane = threadIdx.x & 63;
    if (row >= nrows) return;
    int ps = ptr[row], pe = ptr[row + 1];
    float c0 = 0, c1 = 0, c2 = 0, c3 = 0, c4 = 0, c5 = 0, c6 = 0, c7 = 0;
    for (int k0 = ps; k0 < pe; k0 += 64) {
        int k = k0 + lane;
        int sv = 0, rv = 0;
        if (k < pe) { sv = idx[k]; rv = rel[k]; }
        int kn = min(pe - k0, 64);
        for (int t = 0; t < kn; ++t) {
            int s = __shfl(sv, t, 64);
            int r = __builtin_amdgcn_readfirstlane(__shfl(rv, t, 64));
            float v = bf2f(src[(size_t)s * 64 + lane]);
            switch (r) {
                case 0: c0 += v; break;
                case 1: c1 += v; break;
                case 2: c2 += v; break;
                case 3: c3 += v; break;
                case 4: c4 += v; break;
                case 5: c5 += v; break;
                case 6: c6 += v; break;
                default: c7 += v; break;
            }
        }
    }
    unsigned short* o = A + (size_t)row * DK + lane;
    o[0]   = f2bf(c0);
    o[64]  = f2bf(c1);
    o[128] = f2bf(c2);
    o[192] = f2bf(c3);
    o[256] = f2bf(c4);
    o[320] = f2bf(c5);
    o[384] = f2bf(c6);
    o[448] = f2bf(c7);
}

// ---- GEMM1: [Mp,512] @ BT1[64,512]^T -> relu -> h bf16 [Mp,64]
// Block 256 thr = 4 waves; wave owns 32 rows (2 m-tiles) x 64 cols (4 n-tiles).
// Frags loaded directly from global (B is 64KB, L2-hot; A streamed once).
__global__ __launch_bounds__(256) void k_gemm_relu(
    const unsigned short* __restrict__ A, const unsigned short* __restrict__ BT,
    unsigned short* __restrict__ H, int M) {
    int wave = threadIdx.x >> 6, lane = threadIdx.x & 63;
    int lr = lane & 15, lg = lane >> 4;
    int m0 = blockIdx.x * 128 + wave * 32;
    const unsigned short* Ab = A + (size_t)(m0 + lr) * DK + lg * 8;
    const unsigned short* Bb = BT + (size_t)lr * DK + lg * 8;
    floatx4 acc[2][4] = {};
#pragma unroll 4
    for (int k0 = 0; k0 < DK; k0 += 32) {
        short8 a0 = *(const short8*)(Ab + k0);
        short8 a1 = *(const short8*)(Ab + 16 * DK + k0);
        short8 b0 = *(const short8*)(Bb + k0);
        short8 b1 = *(const short8*)(Bb + 16 * DK + k0);
        short8 b2 = *(const short8*)(Bb + 32 * DK + k0);
        short8 b3 = *(const short8*)(Bb + 48 * DK + k0);
        acc[0][0] = __builtin_amdgcn_mfma_f32_16x16x32_bf16(a0, b0, acc[0][0], 0, 0, 0);
        acc[0][1] = __builtin_amdgcn_mfma_f32_16x16x32_bf16(a0, b1, acc[0][1], 0, 0, 0);
        acc[0][2] = __builtin_amdgcn_mfma_f32_16x16x32_bf16(a0, b2, acc[0][2], 0, 0, 0);
        acc[0][3] = __builtin_amdgcn_mfma_f32_16x16x32_bf16(a0, b3, acc[0][3], 0, 0, 0);
        acc[1][0] = __builtin_amdgcn_mfma_f32_16x16x32_bf16(a1, b0, acc[1][0], 0, 0, 0);
        acc[1][1] = __builtin_amdgcn_mfma_f32_16x16x32_bf16(a1, b1, acc[1][1], 0, 0, 0);
        acc[1][2] = __builtin_amdgcn_mfma_f32_16x16x32_bf16(a1, b2, acc[1][2], 0, 0, 0);
        acc[1][3] = __builtin_amdgcn_mfma_f32_16x16x32_bf16(a1, b3, acc[1][3], 0, 0, 0);
    }
    // C/D layout (m89-verified): col = lane&15, row = (lane>>4)*4 + reg
#pragma unroll
    for (int mt = 0; mt < 2; ++mt)
#pragma unroll
        for (int nt = 0; nt < 4; ++nt)
#pragma unroll
            for (int i = 0; i < 4; ++i) {
                int row = m0 + mt * 16 + lg * 4 + i;
                if (row < M)
                    H[(size_t)row * 64 + nt * 16 + lr] = f2bf(fmaxf(acc[mt][nt][i], 0.0f));
            }
}

// ---- GEMM2: [Mp,512] @ BT2[48,512]^T, fused log_softmax over the 40 valid cols.
__global__ __launch_bounds__(256) void k_gemm_lsm(
    const unsigned short* __restrict__ A, const unsigned short* __restrict__ BT,
    float* __restrict__ out, int M) {
    int wave = threadIdx.x >> 6, lane = threadIdx.x & 63;
    int lr = lane & 15, lg = lane >> 4;
    int m0 = blockIdx.x * 128 + wave * 32;
    const unsigned short* Ab = A + (size_t)(m0 + lr) * DK + lg * 8;
    const unsigned short* Bb = BT + (size_t)lr * DK + lg * 8;
    floatx4 acc[2][3] = {};
#pragma unroll 4
    for (int k0 = 0; k0 < DK; k0 += 32) {
        short8 a0 = *(const short8*)(Ab + k0);
        short8 a1 = *(const short8*)(Ab + 16 * DK + k0);
        short8 b0 = *(const short8*)(Bb + k0);
        short8 b1 = *(const short8*)(Bb + 16 * DK + k0);
        short8 b2 = *(const short8*)(Bb + 32 * DK + k0);   // rows 32..47; 40..47 are pad (masked below)
        acc[0][0] = __builtin_amdgcn_mfma_f32_16x16x32_bf16(a0, b0, acc[0][0], 0, 0, 0);
        acc[0][1] = __builtin_amdgcn_mfma_f32_16x16x32_bf16(a0, b1, acc[0][1], 0, 0, 0);
        acc[0][2] = __builtin_amdgcn_mfma_f32_16x16x32_bf16(a0, b2, acc[0][2], 0, 0, 0);
        acc[1][0] = __builtin_amdgcn_mfma_f32_16x16x32_bf16(a1, b0, acc[1][0], 0, 0, 0);
        acc[1][1] = __builtin_amdgcn_mfma_f32_16x16x32_bf16(a1, b1, acc[1][1], 0, 0, 0);
        acc[1][2] = __builtin_amdgcn_mfma_f32_16x16x32_bf16(a1, b2, acc[1][2], 0, 0, 0);
    }
    bool c2ok = lr < 8;   // n-tile 2 covers cols 32..47; valid iff col < 40
#pragma unroll
    for (int mt = 0; mt < 2; ++mt) {
#pragma unroll
        for (int i = 0; i < 4; ++i) {
            float v0 = acc[mt][0][i], v1 = acc[mt][1][i], v2 = acc[mt][2][i];
            float mx = fmaxf(v0, v1);
            if (c2ok) mx = fmaxf(mx, v2);
#pragma unroll
            for (int off = 1; off < 16; off <<= 1)
                mx = fmaxf(mx, __shfl_xor(mx, off, 16));
            float s = __expf(v0 - mx) + __expf(v1 - mx) + (c2ok ? __expf(v2 - mx) : 0.0f);
#pragma unroll
            for (int off = 1; off < 16; off <<= 1)
                s += __shfl_xor(s, off, 16);
            float lse = mx + __logf(s);
            int row = m0 + mt * 16 + lg * 4 + i;
            if (row < M) {
                float* orow = out + (size_t)row * 40;
                orow[lr] = v0 - lse;
                orow[16 + lr] = v1 - lse;
                if (c2ok) orow[32 + lr] = v2 - lse;
            }
        }
    }
}

extern "C" void kernel_launch(void* const* d_in, const int* in_sizes, int n_in,
                              void* d_out, int out_size, void* d_ws, size_t ws_size,
                              hipStream_t stream) {
    const float* x  = (const float*)d_in[0];
    const int* ptr  = (const int*)d_in[1];
    const int* idx  = (const int*)d_in[2];
    const int* rel  = (const int*)d_in[3];
    const float* W1 = (const float*)d_in[4];
    const float* W2 = (const float*)d_in[5];
    float* out = (float*)d_out;

    int N = in_sizes[1] - 1;                 // 75000
    int MP = (N + 127) & ~127;               // 75008, multiple of 128

    char* ws = (char*)d_ws;
    size_t szRow64 = (size_t)MP * 64 * 2;    // bf16 [MP,64]
    unsigned short* xbf = (unsigned short*)(ws);
    unsigned short* hbf = (unsigned short*)(ws + szRow64);
    unsigned short* BT1 = (unsigned short*)(ws + 2 * szRow64);
    unsigned short* BT2 = (unsigned short*)(ws + 2 * szRow64 + 64 * 512 * 2);
    unsigned short* Abuf = (unsigned short*)(ws + 2 * szRow64 + 64 * 512 * 2 + 48 * 512 * 2);
    // total ws use: 2*9.6MB + 64KB + 48KB + 76.8MB ~= 96.2MB

    int n4 = N * 16;                          // N*64/4 f32 quads
    k_cast<<<(n4 + 255) / 256, 256, 0, stream>>>(x, xbf, n4);
    k_packw<<<(64 * 512 + 40 * 512 + 255) / 256, 256, 0, stream>>>(W1, W2, BT1, BT2);

    int gblocks = (N + 3) / 4;
    k_gather<<<gblocks, 256, 0, stream>>>(xbf, ptr, idx, rel, Abuf, N);
    k_gemm_relu<<<MP / 128, 256, 0, stream>>>(Abuf, BT1, hbf, N);
    k_gather<<<gblocks, 256, 0, stream>>>(hbf, ptr, idx, rel, Abuf, N);
    k_gemm_lsm<<<MP / 128, 256, 0, stream>>>(Abuf, BT2, out, N);
}

// Round 2
// 165.829 us; speedup vs baseline: 1.4813x; 1.4813x over previous
//
#include <hip/hip_runtime.h>
#include <hip/hip_bf16.h>

// RGCN CSR, two layers, on MI355X.
// Reformulation: h[i] = sum_r (sum_{e in row i, rel=r} x[src_e]) @ W1[r]
//  -> gather kernel builds A[N, R*64] (bf16), then one GEMM with K=512.
// Layer 2 identical with W2 (N=40, padded to 48), log_softmax fused.
//
// R1 change: gather rewritten. row forced wave-uniform (readfirstlane) so
// idx/rel come in via scalar loads (no shuffles); all 16 source-row loads
// issued upfront into registers (one latency, not 16 serialized); relation
// dispatch is a scalar branch tree on SGPRs after loads are in flight.

typedef __attribute__((ext_vector_type(8))) short short8;
typedef __attribute__((ext_vector_type(4))) float floatx4;

#define DK 512          // R * D = 8 * 64, flattened K dimension

static __device__ __forceinline__ unsigned short f2bf(float f) {
    unsigned u = __float_as_uint(f);
    u += 0x7FFFu + ((u >> 16) & 1u);      // RNE
    return (unsigned short)(u >> 16);
}
static __device__ __forceinline__ float bf2f(unsigned short h) {
    return __uint_as_float(((unsigned)h) << 16);
}

// ---- cast x (f32) -> bf16, 4 elems/thread ----
__global__ void k_cast(const float* __restrict__ x, unsigned short* __restrict__ o, int n4) {
    int i = blockIdx.x * blockDim.x + threadIdx.x;
    if (i >= n4) return;
    float4 v = ((const float4*)x)[i];
    ushort4 r;
    r.x = f2bf(v.x); r.y = f2bf(v.y); r.z = f2bf(v.z); r.w = f2bf(v.w);
    ((ushort4*)o)[i] = r;
}

// ---- pack W1[r][d][f] -> BT1[f][r*64+d] (bf16), W2 likewise into BT2[40][512] ----
__global__ void k_packw(const float* __restrict__ W1, const float* __restrict__ W2,
                        unsigned short* __restrict__ BT1, unsigned short* __restrict__ BT2) {
    int i = blockIdx.x * 256 + threadIdx.x;
    if (i < 64 * 512) {
        int f = i >> 9, rd = i & 511;
        int r = rd >> 6, d = rd & 63;
        BT1[i] = f2bf(W1[(r << 12) + (d << 6) + f]);
    } else if (i < 64 * 512 + 40 * 512) {
        int j = i - 64 * 512;
        int f = j >> 9, rd = j & 511;
        int r = rd >> 6, d = rd & 63;
        BT2[j] = f2bf(W2[r * 2560 + d * 40 + f]);
    }
}

// ---- gather: one wave per destination row. Row id is wave-uniform ->
// readfirstlane pins it to an SGPR; idx/rel row slices become scalar loads.
// Fast path (deg==16, guaranteed by setup): two-phase — issue all 16
// feature-row loads, then scalar-branch accumulate into 8 relation regs.
__global__ __launch_bounds__(256) void k_gather(
    const unsigned short* __restrict__ src,          // [N, 64] bf16 rows
    const int* __restrict__ ptr, const int* __restrict__ idx,
    const int* __restrict__ rel,
    unsigned short* __restrict__ A, int nrows) {     // [Mp, 512] bf16
    int row = blockIdx.x * 4 + (threadIdx.x >> 6);
    int lane = threadIdx.x & 63;
    if (row >= nrows) return;
    row = __builtin_amdgcn_readfirstlane(row);       // wave-uniform -> SGPR
    int ps = ptr[row], pe = ptr[row + 1];            // scalar loads
    const int* __restrict__ idxr = idx + ps;
    const int* __restrict__ relr = rel + ps;
    int deg = pe - ps;
    float c0 = 0, c1 = 0, c2 = 0, c3 = 0, c4 = 0, c5 = 0, c6 = 0, c7 = 0;
    if (deg == 16) {
        float v[16];
#pragma unroll
        for (int t = 0; t < 16; ++t) {
            int s = idxr[t];                         // SGPR (uniform addr)
            v[t] = bf2f(src[(size_t)s * 64 + lane]); // 16 independent loads in flight
        }
#pragma unroll
        for (int t = 0; t < 16; ++t) {
            int r = relr[t];                         // SGPR
            float x = v[t];
            if (r == 0) c0 += x;
            else if (r == 1) c1 += x;
            else if (r == 2) c2 += x;
            else if (r == 3) c3 += x;
            else if (r == 4) c4 += x;
            else if (r == 5) c5 += x;
            else if (r == 6) c6 += x;
            else c7 += x;
        }
    } else {
        // generic fallback (unused for the regular-degree dataset)
        for (int t = 0; t < deg; ++t) {
            int s = idxr[t];
            int r = relr[t];
            float x = bf2f(src[(size_t)s * 64 + lane]);
            if (r == 0) c0 += x;
            else if (r == 1) c1 += x;
            else if (r == 2) c2 += x;
            else if (r == 3) c3 += x;
            else if (r == 4) c4 += x;
            else if (r == 5) c5 += x;
            else if (r == 6) c6 += x;
            else c7 += x;
        }
    }
    unsigned short* o = A + (size_t)row * DK + lane;
    o[0]   = f2bf(c0);
    o[64]  = f2bf(c1);
    o[128] = f2bf(c2);
    o[192] = f2bf(c3);
    o[256] = f2bf(c4);
    o[320] = f2bf(c5);
    o[384] = f2bf(c6);
    o[448] = f2bf(c7);
}

// ---- GEMM1: [Mp,512] @ BT1[64,512]^T -> relu -> h bf16 [Mp,64]
// Block 256 thr = 4 waves; wave owns 32 rows (2 m-tiles) x 64 cols (4 n-tiles).
// Frags loaded directly from global (B is 64KB, L2-hot; A streamed once).
__global__ __launch_bounds__(256) void k_gemm_relu(
    const unsigned short* __restrict__ A, const unsigned short* __restrict__ BT,
    unsigned short* __restrict__ H, int M) {
    int wave = threadIdx.x >> 6, lane = threadIdx.x & 63;
    int lr = lane & 15, lg = lane >> 4;
    int m0 = blockIdx.x * 128 + wave * 32;
    const unsigned short* Ab = A + (size_t)(m0 + lr) * DK + lg * 8;
    const unsigned short* Bb = BT + (size_t)lr * DK + lg * 8;
    floatx4 acc[2][4] = {};
#pragma unroll 4
    for (int k0 = 0; k0 < DK; k0 += 32) {
        short8 a0 = *(const short8*)(Ab + k0);
        short8 a1 = *(const short8*)(Ab + 16 * DK + k0);
        short8 b0 = *(const short8*)(Bb + k0);
        short8 b1 = *(const short8*)(Bb + 16 * DK + k0);
        short8 b2 = *(const short8*)(Bb + 32 * DK + k0);
        short8 b3 = *(const short8*)(Bb + 48 * DK + k0);
        acc[0][0] = __builtin_amdgcn_mfma_f32_16x16x32_bf16(a0, b0, acc[0][0], 0, 0, 0);
        acc[0][1] = __builtin_amdgcn_mfma_f32_16x16x32_bf16(a0, b1, acc[0][1], 0, 0, 0);
        acc[0][2] = __builtin_amdgcn_mfma_f32_16x16x32_bf16(a0, b2, acc[0][2], 0, 0, 0);
        acc[0][3] = __builtin_amdgcn_mfma_f32_16x16x32_bf16(a0, b3, acc[0][3], 0, 0, 0);
        acc[1][0] = __builtin_amdgcn_mfma_f32_16x16x32_bf16(a1, b0, acc[1][0], 0, 0, 0);
        acc[1][1] = __builtin_amdgcn_mfma_f32_16x16x32_bf16(a1, b1, acc[1][1], 0, 0, 0);
        acc[1][2] = __builtin_amdgcn_mfma_f32_16x16x32_bf16(a1, b2, acc[1][2], 0, 0, 0);
        acc[1][3] = __builtin_amdgcn_mfma_f32_16x16x32_bf16(a1, b3, acc[1][3], 0, 0, 0);
    }
    // C/D layout (m89-verified): col = lane&15, row = (lane>>4)*4 + reg
#pragma unroll
    for (int mt = 0; mt < 2; ++mt)
#pragma unroll
        for (int nt = 0; nt < 4; ++nt)
#pragma unroll
            for (int i = 0; i < 4; ++i) {
                int row = m0 + mt * 16 + lg * 4 + i;
                if (row < M)
                    H[(size_t)row * 64 + nt * 16 + lr] = f2bf(fmaxf(acc[mt][nt][i], 0.0f));
            }
}

// ---- GEMM2: [Mp,512] @ BT2[48,512]^T, fused log_softmax over the 40 valid cols.
__global__ __launch_bounds__(256) void k_gemm_lsm(
    const unsigned short* __restrict__ A, const unsigned short* __restrict__ BT,
    float* __restrict__ out, int M) {
    int wave = threadIdx.x >> 6, lane = threadIdx.x & 63;
    int lr = lane & 15, lg = lane >> 4;
    int m0 = blockIdx.x * 128 + wave * 32;
    const unsigned short* Ab = A + (size_t)(m0 + lr) * DK + lg * 8;
    const unsigned short* Bb = BT + (size_t)lr * DK + lg * 8;
    floatx4 acc[2][3] = {};
#pragma unroll 4
    for (int k0 = 0; k0 < DK; k0 += 32) {
        short8 a0 = *(const short8*)(Ab + k0);
        short8 a1 = *(const short8*)(Ab + 16 * DK + k0);
        short8 b0 = *(const short8*)(Bb + k0);
        short8 b1 = *(const short8*)(Bb + 16 * DK + k0);
        short8 b2 = *(const short8*)(Bb + 32 * DK + k0);   // rows 32..47; 40..47 are pad (masked below)
        acc[0][0] = __builtin_amdgcn_mfma_f32_16x16x32_bf16(a0, b0, acc[0][0], 0, 0, 0);
        acc[0][1] = __builtin_amdgcn_mfma_f32_16x16x32_bf16(a0, b1, acc[0][1], 0, 0, 0);
        acc[0][2] = __builtin_amdgcn_mfma_f32_16x16x32_bf16(a0, b2, acc[0][2], 0, 0, 0);
        acc[1][0] = __builtin_amdgcn_mfma_f32_16x16x32_bf16(a1, b0, acc[1][0], 0, 0, 0);
        acc[1][1] = __builtin_amdgcn_mfma_f32_16x16x32_bf16(a1, b1, acc[1][1], 0, 0, 0);
        acc[1][2] = __builtin_amdgcn_mfma_f32_16x16x32_bf16(a1, b2, acc[1][2], 0, 0, 0);
    }
    bool c2ok = lr < 8;   // n-tile 2 covers cols 32..47; valid iff col < 40
#pragma unroll
    for (int mt = 0; mt < 2; ++mt) {
#pragma unroll
        for (int i = 0; i < 4; ++i) {
            float v0 = acc[mt][0][i], v1 = acc[mt][1][i], v2 = acc[mt][2][i];
            float mx = fmaxf(v0, v1);
            if (c2ok) mx = fmaxf(mx, v2);
#pragma unroll
            for (int off = 1; off < 16; off <<= 1)
                mx = fmaxf(mx, __shfl_xor(mx, off, 16));
            float s = __expf(v0 - mx) + __expf(v1 - mx) + (c2ok ? __expf(v2 - mx) : 0.0f);
#pragma unroll
            for (int off = 1; off < 16; off <<= 1)
                s += __shfl_xor(s, off, 16);
            float lse = mx + __logf(s);
            int row = m0 + mt * 16 + lg * 4 + i;
            if (row < M) {
                float* orow = out + (size_t)row * 40;
                orow[lr] = v0 - lse;
                orow[16 + lr] = v1 - lse;
                if (c2ok) orow[32 + lr] = v2 - lse;
            }
        }
    }
}

extern "C" void kernel_launch(void* const* d_in, const int* in_sizes, int n_in,
                              void* d_out, int out_size, void* d_ws, size_t ws_size,
                              hipStream_t stream) {
    const float* x  = (const float*)d_in[0];
    const int* ptr  = (const int*)d_in[1];
    const int* idx  = (const int*)d_in[2];
    const int* rel  = (const int*)d_in[3];
    const float* W1 = (const float*)d_in[4];
    const float* W2 = (const float*)d_in[5];
    float* out = (float*)d_out;

    int N = in_sizes[1] - 1;                 // 75000
    int MP = (N + 127) & ~127;               // 75008, multiple of 128

    char* ws = (char*)d_ws;
    size_t szRow64 = (size_t)MP * 64 * 2;    // bf16 [MP,64]
    unsigned short* xbf = (unsigned short*)(ws);
    unsigned short* hbf = (unsigned short*)(ws + szRow64);
    unsigned short* BT1 = (unsigned short*)(ws + 2 * szRow64);
    unsigned short* BT2 = (unsigned short*)(ws + 2 * szRow64 + 64 * 512 * 2);
    unsigned short* Abuf = (unsigned short*)(ws + 2 * szRow64 + 64 * 512 * 2 + 48 * 512 * 2);
    // total ws use: 2*9.6MB + 64KB + 48KB + 76.8MB ~= 96.2MB

    int n4 = N * 16;                          // N*64/4 f32 quads
    k_cast<<<(n4 + 255) / 256, 256, 0, stream>>>(x, xbf, n4);
    k_packw<<<(64 * 512 + 40 * 512 + 255) / 256, 256, 0, stream>>>(W1, W2, BT1, BT2);

    int gblocks = (N + 3) / 4;
    k_gather<<<gblocks, 256, 0, stream>>>(xbf, ptr, idx, rel, Abuf, N);
    k_gemm_relu<<<MP / 128, 256, 0, stream>>>(Abuf, BT1, hbf, N);
    k_gather<<<gblocks, 256, 0, stream>>>(hbf, ptr, idx, rel, Abuf, N);
    k_gemm_lsm<<<MP / 128, 256, 0, stream>>>(Abuf, BT2, out, N);
}